// Round 1
// baseline (516.604 us; speedup 1.0000x reference)
//
#include <hip/hip_runtime.h>
#include <stdint.h>

// Problem constants (from reference setup_inputs)
#define T_TOK 1024
#define K_IN  4096
#define N_OUT 6144
#define N_Q   4096
#define N_KV  1024
#define N_D   4
#define KP    512          // K_IN/8 packed int32 per row

// GEMM tiling
#define TM 128
#define TN 128
#define BK 64
#define KSPLIT 2
#define KHALF (K_IN / KSPLIT)   // 2048
#define NSTEPS (KHALF / BK)     // 32
#define PM_MAX 1536        // >= 1024 + 4*127 rounded up; fixed grid bound
#define MT (PM_MAX/TM)     // 12
#define NT (N_OUT/TN)      // 48
#define NBLK (NT * MT * KSPLIT) // 1152

typedef __attribute__((ext_vector_type(8)))  short  short8;   // 8 x bf16 (4 VGPR) MFMA A/B frag
typedef __attribute__((ext_vector_type(4)))  float  float4v;  // MFMA C/D frag
typedef __attribute__((ext_vector_type(4)))  float  f32x4;
typedef __attribute__((ext_vector_type(4)))  uint   u32x4;

__device__ __forceinline__ ushort f2bf(float f) {
    uint32_t u = __float_as_uint(f);
    u = (u + 0x7FFFu + ((u >> 16) & 1u)) >> 16;   // RNE
    return (ushort)u;
}
__device__ __forceinline__ uint pack2(ushort a, ushort b) {
    return (uint)a | ((uint)b << 16);
}

// 8 nibbles of q -> short8 of bf16 values (128 + nib), exact.
// bf16 0x4300 = 128.0; mantissa has 7 bits so 128+n (n<=15) is exact.
// The +128 offset and the GPTQ zero-point are corrected in the epilogue
// via the row-sum of A:  s*acc_nib - s*(129+z)*rowsum(A).
__device__ __forceinline__ short8 unpack_nib(uint q) {
    union { u32x4 u; short8 s; } r;
    uint t1 = q >> 8, t2 = q >> 16, t3 = q >> 24;
    r.u.x = ((q  & 0xFu) | ((q  & 0xF0u) << 12)) | 0x43004300u;
    r.u.y = ((t1 & 0xFu) | ((t1 & 0xF0u) << 12)) | 0x43004300u;
    r.u.z = ((t2 & 0xFu) | ((t2 & 0xF0u) << 12)) | 0x43004300u;
    r.u.w = ((t3 & 0xFu) | ((t3 & 0xF0u) << 12)) | 0x43004300u;
    return r.s;
}

// ---------------------------------------------------------------------------
// K1: group tokens by adapter. perm[PM_MAX] = token index or -1 (padding);
// pofs[d] = padded segment starts (multiples of TM), pofs[N_D] = padded total.
// ---------------------------------------------------------------------------
__global__ void build_perm_kernel(const int* __restrict__ indices,
                                  int* __restrict__ perm,
                                  int* __restrict__ pofs) {
    __shared__ int cnt[N_D], cur[N_D], ps[N_D + 1];
    int tid = threadIdx.x;
    if (tid < N_D) { cnt[tid] = 0; cur[tid] = 0; }
    __syncthreads();
    for (int t = tid; t < T_TOK; t += blockDim.x) atomicAdd(&cnt[indices[t]], 1);
    for (int p = tid; p < PM_MAX; p += blockDim.x) perm[p] = -1;
    __syncthreads();
    if (tid == 0) {
        int run = 0;
        for (int d = 0; d < N_D; d++) { ps[d] = run; run += ((cnt[d] + TM - 1) / TM) * TM; }
        ps[N_D] = run;
        for (int d = 0; d <= N_D; d++) pofs[d] = ps[d];
    }
    __syncthreads();
    for (int t = tid; t < T_TOK; t += blockDim.x) {
        int d = indices[t];
        int r = atomicAdd(&cur[d], 1);
        perm[ps[d] + r] = t;   // slot order arbitrary; per-token result independent of slot
    }
}

// ---------------------------------------------------------------------------
// K2: wb16[o][k] = bf16(w_base[o][k]).  (was: 201 MB dequant wall; now 50 MB,
// shared by all 4 adapters -- the delta is dequantized inside the GEMM.)
// ---------------------------------------------------------------------------
__global__ void wbconv_kernel(const float* __restrict__ w_base,
                              ushort* __restrict__ wb16) {
    int id = blockIdx.x * blockDim.x + threadIdx.x;   // [0, N_OUT*K_IN/8)
    const f32x4* src = (const f32x4*)(w_base + (size_t)id * 8);
    f32x4 a = __builtin_nontemporal_load(src);
    f32x4 b = __builtin_nontemporal_load(src + 1);
    u32x4 packv;
    packv.x = pack2(f2bf(a.x), f2bf(a.y));
    packv.y = pack2(f2bf(a.z), f2bf(a.w));
    packv.z = pack2(f2bf(b.x), f2bf(b.y));
    packv.w = pack2(f2bf(b.z), f2bf(b.w));
    *(u32x4*)(wb16 + (size_t)id * 8) = packv;   // keep cached: GEMM B-stream
}

// ---------------------------------------------------------------------------
// K3: Xp[pm][k] = bf16(x[perm[pm]][k]) or 0 for padding rows.
// Also emits rs[pm][half] = sum_k(bf16 A values) over each K-half, used by the
// GEMM epilogue to correct the (128+nib) offset and the zero-point.
// ---------------------------------------------------------------------------
__global__ void build_xp_kernel(const float* __restrict__ x,
                                const int* __restrict__ perm,
                                ushort* __restrict__ xp,
                                float* __restrict__ rs) {
    int pm = blockIdx.x;
    int half = blockIdx.y;
    int c0 = half * KHALF + threadIdx.x * 8;
    int tok = perm[pm];
    ushort res[8];
    if (tok < 0) {
#pragma unroll
        for (int j = 0; j < 8; j++) res[j] = 0;
    } else {
        const f32x4* src = (const f32x4*)(x + (size_t)tok * K_IN + c0);
        f32x4 a = __builtin_nontemporal_load(src);
        f32x4 b = __builtin_nontemporal_load(src + 1);
        float v[8] = {a.x, a.y, a.z, a.w, b.x, b.y, b.z, b.w};
#pragma unroll
        for (int j = 0; j < 8; j++) res[j] = f2bf(v[j]);
    }
    u32x4 packv;
    packv.x = pack2(res[0], res[1]); packv.y = pack2(res[2], res[3]);
    packv.z = pack2(res[4], res[5]); packv.w = pack2(res[6], res[7]);
    *(u32x4*)(xp + (size_t)pm * K_IN + c0) = packv;

    // row-sum of the EXACT bf16 values the MFMA will consume
    float ssum = 0.f;
#pragma unroll
    for (int j = 0; j < 8; j++) ssum += __uint_as_float((uint)res[j] << 16);
#pragma unroll
    for (int off = 32; off > 0; off >>= 1) ssum += __shfl_xor(ssum, off);
    __shared__ float wsum[4];
    if ((threadIdx.x & 63) == 0) wsum[threadIdx.x >> 6] = ssum;
    __syncthreads();
    if (threadIdx.x == 0) rs[pm * 2 + half] = wsum[0] + wsum[1] + wsum[2] + wsum[3];
}

// ---------------------------------------------------------------------------
// K4: out[t][n] = bias[n] (split-K accumulators atomicAdd on top).
// ---------------------------------------------------------------------------
__global__ void init_out_kernel(const float* __restrict__ bias,
                                float* __restrict__ out) {
    int id = blockIdx.x * blockDim.x + threadIdx.x;     // [0, T*N_OUT/4)
    int n4 = id & (N_OUT / 4 - 1);                      // N_OUT/4 = 1536
    int t  = id / (N_OUT / 4);
    float4 b = *(const float4*)(bias + n4 * 4);
    *(float4*)(out + (size_t)t * N_OUT + n4 * 4) = b;
}

// ---------------------------------------------------------------------------
// K5: split-K GEMM with fused GPTQ delta.
// Base path: LDS-staged shared wb16 B-tile (global_load_lds, XOR swizzle).
// Delta path: packed qw int32 prefetched to registers one step ahead, unpacked
// to bf16 (128+nib) frags with pure bit-ops, fed to a second MFMA chain.
// Epilogue: out += acc_base + s*acc_nib - s*(129+z)*rowsumA.
// ---------------------------------------------------------------------------
__global__ __launch_bounds__(256, 2) void gemm_kernel(
    const ushort* __restrict__ xp, const ushort* __restrict__ wb16,
    const int* __restrict__ qw_q, const int* __restrict__ qw_k, const int* __restrict__ qw_v,
    const int* __restrict__ qz_q, const int* __restrict__ qz_k, const int* __restrict__ qz_v,
    const float* __restrict__ sc_q, const float* __restrict__ sc_k, const float* __restrict__ sc_v,
    const int* __restrict__ perm, const int* __restrict__ pofs,
    const float* __restrict__ rs,
    float* __restrict__ out) {

    __shared__ ushort As[2][TM * BK];   // 2 x 16 KB
    __shared__ ushort Bs[2][TN * BK];   // 2 x 16 KB

    // XCD-pinned decode: lin = 8*(bq*24 + j) + low3; bn = bq*8+low3
    int lin  = blockIdx.x;
    int low3 = lin & 7, rest = lin >> 3;
    int j    = rest % 24, bq = rest / 24;
    int bn   = bq * 8 + low3;
    int bm   = j % MT, kz = j / MT;

    int m0 = bm * TM, n0 = bn * TN;
    int ptot = pofs[N_D];
    if (m0 >= ptot) return;                       // uniform per block
    int d = 0;
    while (d < N_D - 1 && m0 >= pofs[d + 1]) d++; // tile fully inside segment d

    // section select (n-tile never straddles q/k/v: all multiples of TN)
    const int* qw; const int* qz; const float* sc; int r0, Osec;
    if (n0 < N_Q)            { qw = qw_q; qz = qz_q; sc = sc_q; r0 = n0;                Osec = N_Q;  }
    else if (n0 < N_Q + N_KV){ qw = qw_k; qz = qz_k; sc = sc_k; r0 = n0 - N_Q;          Osec = N_KV; }
    else                     { qw = qw_v; qz = qz_v; sc = sc_v; r0 = n0 - (N_Q + N_KV); Osec = N_KV; }

    int tid  = threadIdx.x;
    int lane = tid & 63;
    int wv   = tid >> 6;
    int wm   = (wv & 1) * 64;
    int wn   = (wv >> 1) * 64;
    int quad = lane >> 4;
    int l16  = lane & 15;
    int xa   = l16 & 7;          // read-side swizzle term

    // per-lane delta-row bases (B-frag row rsec = section-local output index)
    int    rsec[4];
    size_t qrow[4];
#pragma unroll
    for (int jj = 0; jj < 4; jj++) {
        rsec[jj] = r0 + wn + jj * 16 + l16;
        qrow[jj] = ((size_t)d * Osec + rsec[jj]) * KP;
    }

    const float4v zero4 = {0.f, 0.f, 0.f, 0.f};
    float4v acc_b[4][4], acc_d[4][4];
#pragma unroll
    for (int i = 0; i < 4; i++)
#pragma unroll
        for (int jj = 0; jj < 4; jj++) { acc_b[i][jj] = zero4; acc_d[i][jj] = zero4; }

    // stage one BK-tile (A+B) into the given LDS buffers; 16B/lane, XOR swizzle
    auto stage = [&](ushort* dstA, ushort* dstB, int k0) {
#pragma unroll
        for (int w = 0; w < 4; w++) {
            int p   = w * 256 + tid;
            int row = p >> 3;
            int ckl = (p & 7) ^ (row & 7);
            const ushort* ga = xp   + (size_t)(m0 + row) * K_IN + k0 + ckl * 8;
            const ushort* gb = wb16 + (size_t)(n0 + row) * K_IN + k0 + ckl * 8;
            int base = (w * 256 + (tid & ~63)) * 8;   // wave-uniform ushort offset
            __builtin_amdgcn_global_load_lds((const __attribute__((address_space(1))) void*)ga,
                                             (__attribute__((address_space(3))) void*)(dstA + base), 16, 0, 0);
            __builtin_amdgcn_global_load_lds((const __attribute__((address_space(1))) void*)gb,
                                             (__attribute__((address_space(3))) void*)(dstB + base), 16, 0, 0);
        }
    };

    int kbase = kz * KHALF;
    int buf = 0;
    stage(As[0], Bs[0], kbase);

    // qw prefetch registers: [jj][h], h=0 -> kk=0..31, h=1 -> kk=32..63
    int q_cur[4][2], q_nxt[4][2];
    {
        int qo = kbase >> 3;
#pragma unroll
        for (int jj = 0; jj < 4; jj++)
#pragma unroll
            for (int h = 0; h < 2; h++)
                q_cur[jj][h] = qw[qrow[jj] + qo + h * 4 + quad];
    }
    __syncthreads();

    for (int s = 0; s < NSTEPS; s++) {
        if (s + 1 < NSTEPS) {
            stage(As[1 - buf], Bs[1 - buf], kbase + (s + 1) * BK);
            int qo = (kbase + (s + 1) * BK) >> 3;
#pragma unroll
            for (int jj = 0; jj < 4; jj++)
#pragma unroll
                for (int h = 0; h < 2; h++)
                    q_nxt[jj][h] = qw[qrow[jj] + qo + h * 4 + quad];
        }

        const ushort* Ab = As[buf];
        const ushort* Bb = Bs[buf];
#pragma unroll
        for (int kk = 0; kk < BK; kk += 32) {
            int h   = kk >> 5;
            int ckb = (kk >> 3) + quad;      // 16B-chunk column wanted
            short8 a[4], b[4], bd[4];
#pragma unroll
            for (int i = 0; i < 4; i++)
                a[i] = *(const short8*)(Ab + (wm + i * 16 + l16) * BK + (ckb ^ xa) * 8);
#pragma unroll
            for (int jj = 0; jj < 4; jj++)
                b[jj] = *(const short8*)(Bb + (wn + jj * 16 + l16) * BK + (ckb ^ xa) * 8);
#pragma unroll
            for (int jj = 0; jj < 4; jj++)
                bd[jj] = unpack_nib((uint)q_cur[jj][h]);
#pragma unroll
            for (int i = 0; i < 4; i++)
#pragma unroll
                for (int jj = 0; jj < 4; jj++) {
                    acc_b[i][jj] = __builtin_amdgcn_mfma_f32_16x16x32_bf16(a[i], b[jj],  acc_b[i][jj], 0, 0, 0);
                    acc_d[i][jj] = __builtin_amdgcn_mfma_f32_16x16x32_bf16(a[i], bd[jj], acc_d[i][jj], 0, 0, 0);
                }
        }
        __syncthreads();   // drains next tile's loads + protects buf for re-stage
#pragma unroll
        for (int jj = 0; jj < 4; jj++)
#pragma unroll
            for (int h = 0; h < 2; h++)
                q_cur[jj][h] = q_nxt[jj][h];
        buf ^= 1;
    }

    // epilogue: C/D layout col = lane&15, row = quad*4 + reg  [m89/m91 verified]
    // out += acc_b + s*acc_d - s*(129+z)*rowsumA   (bias already in out)
    float s4[4], cc4[4];
#pragma unroll
    for (int jj = 0; jj < 4; jj++) {
        float sv = sc[(size_t)d * Osec + rsec[jj]];
        int   zq = qz[(size_t)d * (Osec >> 3) + (rsec[jj] >> 3)];
        int   z  = (zq >> ((rsec[jj] & 7) * 4)) & 0xF;
        s4[jj]  = sv;
        cc4[jj] = sv * (float)(129 + z);
    }
#pragma unroll
    for (int i = 0; i < 4; i++) {
        int toks[4]; float rsv[4];
#pragma unroll
        for (int r = 0; r < 4; r++) {
            int row = m0 + wm + i * 16 + quad * 4 + r;
            toks[r] = perm[row];
            rsv[r]  = rs[row * 2 + kz];
        }
#pragma unroll
        for (int jj = 0; jj < 4; jj++) {
            int col = n0 + wn + jj * 16 + l16;
#pragma unroll
            for (int r = 0; r < 4; r++) {
                int tok = toks[r];
                if (tok >= 0) {
                    float v = acc_b[i][jj][r] + s4[jj] * acc_d[i][jj][r] - cc4[jj] * rsv[r];
                    atomicAdd(out + (size_t)tok * N_OUT + col, v);
                }
            }
        }
    }
}

// ---------------------------------------------------------------------------
extern "C" void kernel_launch(void* const* d_in, const int* in_sizes, int n_in,
                              void* d_out, int out_size, void* d_ws, size_t ws_size,
                              hipStream_t stream) {
    const float* x      = (const float*)d_in[0];
    const float* w_base = (const float*)d_in[1];
    const float* bias   = (const float*)d_in[2];
    const int*   qw_q   = (const int*)d_in[3];
    const int*   qw_k   = (const int*)d_in[4];
    const int*   qw_v   = (const int*)d_in[5];
    const int*   qz_q   = (const int*)d_in[6];
    const int*   qz_k   = (const int*)d_in[7];
    const int*   qz_v   = (const int*)d_in[8];
    const float* sc_q   = (const float*)d_in[9];
    const float* sc_k   = (const float*)d_in[10];
    const float* sc_v   = (const float*)d_in[11];
    const int*   indices= (const int*)d_in[12];
    float* out = (float*)d_out;

    // workspace: wb16 bf16 [6144][4096] | Xp bf16 [1536][4096] | rs [1536][2] | perm | pofs
    char* ws = (char*)d_ws;
    ushort* wb16 = (ushort*)ws;
    size_t wb_bytes = (size_t)N_OUT * K_IN * 2;                   // 50331648
    ushort* xp = (ushort*)(ws + wb_bytes);
    size_t xp_bytes = (size_t)PM_MAX * K_IN * 2;                  // 12582912
    float* rsum = (float*)(ws + wb_bytes + xp_bytes);
    size_t rs_bytes = (size_t)PM_MAX * KSPLIT * sizeof(float);    // 12288
    int* perm = (int*)(ws + wb_bytes + xp_bytes + rs_bytes);
    int* pofs = perm + PM_MAX;

    build_perm_kernel<<<1, 256, 0, stream>>>(indices, perm, pofs);
    wbconv_kernel<<<(N_OUT * K_IN / 8) / 256, 256, 0, stream>>>(w_base, wb16);
    build_xp_kernel<<<dim3(PM_MAX, 2), 256, 0, stream>>>(x, perm, xp, rsum);
    init_out_kernel<<<(T_TOK * N_OUT / 4) / 256, 256, 0, stream>>>(bias, out);
    gemm_kernel<<<NBLK, 256, 0, stream>>>(xp, wb16,
        qw_q, qw_k, qw_v, qz_q, qz_k, qz_v, sc_q, sc_k, sc_v,
        perm, pofs, rsum, out);
}

// Round 2
// 443.049 us; speedup vs baseline: 1.1660x; 1.1660x over previous
//
#include <hip/hip_runtime.h>
#include <stdint.h>

// Problem constants (from reference setup_inputs)
#define T_TOK 1024
#define K_IN  4096
#define N_OUT 6144
#define N_Q   4096
#define N_KV  1024
#define N_D   4
#define KP    512          // K_IN/8 packed int32 per row

// GEMM tiling
#define TM 128
#define TN 128
#define BK 64
#define NSTEPS (K_IN / BK)      // 64
#define PM_MAX 1536        // >= 1024 + 4*127 rounded up; fixed grid bound
#define MT (PM_MAX/TM)     // 12
#define NT (N_OUT/TN)      // 48
#define NBLK (NT * MT)     // 576

typedef __attribute__((ext_vector_type(8)))  short  short8;   // 8 x bf16 (4 VGPR) MFMA A/B frag
typedef __attribute__((ext_vector_type(4)))  float  float4v;  // MFMA C/D frag
typedef __attribute__((ext_vector_type(4)))  float  f32x4;
typedef __attribute__((ext_vector_type(4)))  uint   u32x4;

__device__ __forceinline__ ushort f2bf(float f) {
    uint32_t u = __float_as_uint(f);
    u = (u + 0x7FFFu + ((u >> 16) & 1u)) >> 16;   // RNE
    return (ushort)u;
}
__device__ __forceinline__ uint pack2(ushort a, ushort b) {
    return (uint)a | ((uint)b << 16);
}

// 8 nibbles of q -> short8 of bf16 values (128 + nib), exact.
// bf16 0x4300 = 128.0; mantissa has 7 bits so 128+n (n<=15) is exact.
// The +128 offset and the GPTQ zero-point are corrected in the epilogue
// via the row-sum of A:  s*acc_nib - s*(129+z)*rowsum(A).
__device__ __forceinline__ short8 unpack_nib(uint q) {
    union { u32x4 u; short8 s; } r;
    uint t1 = q >> 8, t2 = q >> 16, t3 = q >> 24;
    r.u.x = ((q  & 0xFu) | ((q  & 0xF0u) << 12)) | 0x43004300u;
    r.u.y = ((t1 & 0xFu) | ((t1 & 0xF0u) << 12)) | 0x43004300u;
    r.u.z = ((t2 & 0xFu) | ((t2 & 0xF0u) << 12)) | 0x43004300u;
    r.u.w = ((t3 & 0xFu) | ((t3 & 0xF0u) << 12)) | 0x43004300u;
    return r.s;
}

// ---------------------------------------------------------------------------
// K1: group tokens by adapter. perm[PM_MAX] = token index or -1 (padding);
// pofs[d] = padded segment starts (multiples of TM), pofs[N_D] = padded total.
// Wave-ballot ranking: zero atomics (old version serialized ~2k LDS atomics
// on 4 addresses in a single block).
// ---------------------------------------------------------------------------
__global__ void build_perm_kernel(const int* __restrict__ indices,
                                  int* __restrict__ perm,
                                  int* __restrict__ pofs) {
    int tid = threadIdx.x;
    for (int p = tid; p < PM_MAX; p += 256) perm[p] = -1;
    __syncthreads();
    if (tid >= 64) return;              // single wave does the ranking

    // pass 1: counts (wave-uniform accumulation via ballots)
    int cnt0 = 0, cnt1 = 0, cnt2 = 0, cnt3 = 0;
#pragma unroll
    for (int it = 0; it < T_TOK / 64; it++) {
        int d = indices[it * 64 + tid];
        cnt0 += __popcll(__ballot(d == 0));
        cnt1 += __popcll(__ballot(d == 1));
        cnt2 += __popcll(__ballot(d == 2));
        cnt3 += __popcll(__ballot(d == 3));
    }
    int cnt[4] = {cnt0, cnt1, cnt2, cnt3};
    int ps[5];
    int run = 0;
#pragma unroll
    for (int d = 0; d < N_D; d++) { ps[d] = run; run += ((cnt[d] + TM - 1) / TM) * TM; }
    ps[N_D] = run;
    if (tid == 0) {
#pragma unroll
        for (int d = 0; d <= N_D; d++) pofs[d] = ps[d];
    }
    // pass 2: stable scatter via ballot prefix ranks
    unsigned long long ltmask = (tid == 63) ? 0x7FFFFFFFFFFFFFFFull
                                            : ((1ull << tid) - 1ull);
    int base[4] = {0, 0, 0, 0};
#pragma unroll
    for (int it = 0; it < T_TOK / 64; it++) {
        int d = indices[it * 64 + tid];
        unsigned long long m0 = __ballot(d == 0);
        unsigned long long m1 = __ballot(d == 1);
        unsigned long long m2 = __ballot(d == 2);
        unsigned long long m3 = __ballot(d == 3);
        unsigned long long md = (d == 0) ? m0 : (d == 1) ? m1 : (d == 2) ? m2 : m3;
        int rank = (int)__popcll(md & ltmask);
        int bse  = (d == 0) ? base[0] : (d == 1) ? base[1] : (d == 2) ? base[2] : base[3];
        int psd  = (d == 0) ? ps[0]   : (d == 1) ? ps[1]   : (d == 2) ? ps[2]   : ps[3];
        perm[psd + bse + rank] = it * 64 + tid;
        base[0] += __popcll(m0); base[1] += __popcll(m1);
        base[2] += __popcll(m2); base[3] += __popcll(m3);
    }
}

// ---------------------------------------------------------------------------
// K2: wb16[o][k] = bf16(w_base[o][k]).  50 MB, shared by all 4 adapters --
// the delta is dequantized inside the GEMM.
// ---------------------------------------------------------------------------
__global__ void wbconv_kernel(const float* __restrict__ w_base,
                              ushort* __restrict__ wb16) {
    int id = blockIdx.x * blockDim.x + threadIdx.x;   // [0, N_OUT*K_IN/8)
    const f32x4* src = (const f32x4*)(w_base + (size_t)id * 8);
    f32x4 a = __builtin_nontemporal_load(src);
    f32x4 b = __builtin_nontemporal_load(src + 1);
    u32x4 packv;
    packv.x = pack2(f2bf(a.x), f2bf(a.y));
    packv.y = pack2(f2bf(a.z), f2bf(a.w));
    packv.z = pack2(f2bf(b.x), f2bf(b.y));
    packv.w = pack2(f2bf(b.z), f2bf(b.w));
    *(u32x4*)(wb16 + (size_t)id * 8) = packv;   // keep cached: GEMM B-stream
}

// ---------------------------------------------------------------------------
// K2b: repack qw into GEMM-lane order so the delta operand loads coalesced.
// qp layout: [bn(48)][d(4)][w2(2)][s(64)][lane(64)][8 ints (jj*2+h)], where
// lane = quad*16+l16 matches the GEMM's MFMA B-frag lane, rows jj*16+l16,
// ints col = s*8 + h*4 + quad.  One block per (bn,d,w2,s8): LDS transpose,
// coalesced read (dwordx4 along rows) and coalesced write (32B packets).
// ---------------------------------------------------------------------------
__global__ void repack_qw_kernel(const int* __restrict__ qw_q,
                                 const int* __restrict__ qw_k,
                                 const int* __restrict__ qw_v,
                                 uint* __restrict__ qp) {
    int b  = blockIdx.x;               // [0, 48*4*2*8)
    int s8 = b & 7;
    int r  = b >> 3;
    int w2 = r & 1; r >>= 1;
    int d  = r & 3;
    int bn = r >> 2;
    const int* qw; int r0, Osec;
    if (bn < 32)      { qw = qw_q; r0 = bn * 128;        Osec = N_Q;  }
    else if (bn < 40) { qw = qw_k; r0 = (bn - 32) * 128; Osec = N_KV; }
    else              { qw = qw_v; r0 = (bn - 40) * 128; Osec = N_KV; }

    __shared__ int lds[64 * 64];
    int tid = threadIdx.x;
#pragma unroll
    for (int k = 0; k < 4; k++) {
        int p   = k * 256 + tid;       // dwordx4 index [0,1024)
        int row = p >> 4, c4 = p & 15;
        const int* src = qw + ((size_t)d * Osec + r0 + w2 * 64 + row) * KP + s8 * 64 + c4 * 4;
        *(u32x4*)&lds[row * 64 + c4 * 4] = *(const u32x4*)src;
    }
    __syncthreads();
    size_t obase = (size_t)b * 4096;   // 4096 uints per block slab
#pragma unroll
    for (int k = 0; k < 2; k++) {
        int p    = k * 256 + tid;      // packet index [0,512)
        int sl   = p >> 6, lane = p & 63;
        int quad = lane >> 4, l16 = lane & 15;
        uint pk[8];
#pragma unroll
        for (int e = 0; e < 8; e++) {
            int jj = e >> 1, h = e & 1;
            pk[e] = (uint)lds[(jj * 16 + l16) * 64 + sl * 8 + h * 4 + quad];
        }
        *(u32x4*)(qp + obase + (size_t)p * 8)     = *(u32x4*)&pk[0];
        *(u32x4*)(qp + obase + (size_t)p * 8 + 4) = *(u32x4*)&pk[4];
    }
}

// ---------------------------------------------------------------------------
// K3: Xp[pm][k] = bf16(x[perm[pm]][k]) or 0 for padding rows.
// Also emits rs[pm][half] = sum_k(bf16 A values) per K-half; epilogue sums
// both halves for the (128+nib)/zero-point correction.
// ---------------------------------------------------------------------------
__global__ void build_xp_kernel(const float* __restrict__ x,
                                const int* __restrict__ perm,
                                ushort* __restrict__ xp,
                                float* __restrict__ rs) {
    int pm = blockIdx.x;
    int half = blockIdx.y;
    int c0 = half * (K_IN / 2) + threadIdx.x * 8;
    int tok = perm[pm];
    ushort res[8];
    if (tok < 0) {
#pragma unroll
        for (int j = 0; j < 8; j++) res[j] = 0;
    } else {
        const f32x4* src = (const f32x4*)(x + (size_t)tok * K_IN + c0);
        f32x4 a = __builtin_nontemporal_load(src);
        f32x4 b = __builtin_nontemporal_load(src + 1);
        float v[8] = {a.x, a.y, a.z, a.w, b.x, b.y, b.z, b.w};
#pragma unroll
        for (int j = 0; j < 8; j++) res[j] = f2bf(v[j]);
    }
    u32x4 packv;
    packv.x = pack2(res[0], res[1]); packv.y = pack2(res[2], res[3]);
    packv.z = pack2(res[4], res[5]); packv.w = pack2(res[6], res[7]);
    *(u32x4*)(xp + (size_t)pm * K_IN + c0) = packv;

    // row-sum of the EXACT bf16 values the MFMA will consume
    float ssum = 0.f;
#pragma unroll
    for (int j = 0; j < 8; j++) ssum += __uint_as_float((uint)res[j] << 16);
#pragma unroll
    for (int off = 32; off > 0; off >>= 1) ssum += __shfl_xor(ssum, off);
    __shared__ float wsum[4];
    if ((threadIdx.x & 63) == 0) wsum[threadIdx.x >> 6] = ssum;
    __syncthreads();
    if (threadIdx.x == 0) rs[pm * 2 + half] = wsum[0] + wsum[1] + wsum[2] + wsum[3];
}

// ---------------------------------------------------------------------------
// K4: full-K GEMM with fused GPTQ delta (no split-K, direct store).
// Base path: LDS-staged shared wb16 B-tile (global_load_lds, XOR swizzle).
// Delta path: repacked qp packets, 2 coalesced dwordx4 per lane per step,
// prefetched one step ahead; unpacked to bf16 (128+nib) frags with bit-ops,
// fed to a second MFMA chain.
// Epilogue: out = bias + acc_base + s*acc_nib - s*(129+z)*rowsumA.
// ---------------------------------------------------------------------------
__global__ __launch_bounds__(256, 2) void gemm_kernel(
    const ushort* __restrict__ xp, const ushort* __restrict__ wb16,
    const uint* __restrict__ qp,
    const int* __restrict__ qz_q, const int* __restrict__ qz_k, const int* __restrict__ qz_v,
    const float* __restrict__ sc_q, const float* __restrict__ sc_k, const float* __restrict__ sc_v,
    const float* __restrict__ bias,
    const int* __restrict__ perm, const int* __restrict__ pofs,
    const float* __restrict__ rs,
    float* __restrict__ out) {

    __shared__ ushort As[2][TM * BK];   // 2 x 16 KB
    __shared__ ushort Bs[2][TN * BK];   // 2 x 16 KB

    // XCD-pinned decode: all blocks of one bn share lin%8 -> same XCD L2.
    int lin  = blockIdx.x;              // [0, 576)
    int low3 = lin & 7, rest = lin >> 3;
    int bm   = rest % MT, bq = rest / MT;
    int bn   = bq * 8 + low3;

    int m0 = bm * TM, n0 = bn * TN;
    int ptot = pofs[N_D];
    if (m0 >= ptot) return;                       // uniform per block
    int d = 0;
    while (d < N_D - 1 && m0 >= pofs[d + 1]) d++; // tile fully inside segment d

    int tid  = threadIdx.x;
    int lane = tid & 63;
    int wv   = tid >> 6;
    int wm   = (wv & 1) * 64;
    int wn   = (wv >> 1) * 64;
    int quad = lane >> 4;
    int l16  = lane & 15;
    int xa   = l16 & 7;          // read-side swizzle term

    // delta packet base for this wave: qp[bn][d][w2][s][lane][8]
    const uint* qpw = qp + (((size_t)(bn * 4 + d) * 2 + (wv >> 1)) * 64 * 64 * 8)
                         + (size_t)lane * 8;

    const float4v zero4 = {0.f, 0.f, 0.f, 0.f};
    float4v acc_b[4][4], acc_d[4][4];
#pragma unroll
    for (int i = 0; i < 4; i++)
#pragma unroll
        for (int jj = 0; jj < 4; jj++) { acc_b[i][jj] = zero4; acc_d[i][jj] = zero4; }

    // stage one BK-tile (A+B) into the given LDS buffers; 16B/lane, XOR swizzle
    auto stage = [&](ushort* dstA, ushort* dstB, int k0) {
#pragma unroll
        for (int w = 0; w < 4; w++) {
            int p   = w * 256 + tid;
            int row = p >> 3;
            int ckl = (p & 7) ^ (row & 7);
            const ushort* ga = xp   + (size_t)(m0 + row) * K_IN + k0 + ckl * 8;
            const ushort* gb = wb16 + (size_t)(n0 + row) * K_IN + k0 + ckl * 8;
            int base = (w * 256 + (tid & ~63)) * 8;   // wave-uniform ushort offset
            __builtin_amdgcn_global_load_lds((const __attribute__((address_space(1))) void*)ga,
                                             (__attribute__((address_space(3))) void*)(dstA + base), 16, 0, 0);
            __builtin_amdgcn_global_load_lds((const __attribute__((address_space(1))) void*)gb,
                                             (__attribute__((address_space(3))) void*)(dstB + base), 16, 0, 0);
        }
    };

    int buf = 0;
    stage(As[0], Bs[0], 0);
    uint q_cur[8];
    *(u32x4*)&q_cur[0] = *(const u32x4*)(qpw);
    *(u32x4*)&q_cur[4] = *(const u32x4*)(qpw + 4);
    __syncthreads();

    for (int s = 0; s < NSTEPS; s++) {
        uint q_nxt[8];
        if (s + 1 < NSTEPS) {
            stage(As[1 - buf], Bs[1 - buf], (s + 1) * BK);
            const uint* qn = qpw + (size_t)(s + 1) * 512;
            *(u32x4*)&q_nxt[0] = *(const u32x4*)(qn);
            *(u32x4*)&q_nxt[4] = *(const u32x4*)(qn + 4);
        }

        const ushort* Ab = As[buf];
        const ushort* Bb = Bs[buf];
#pragma unroll
        for (int kk = 0; kk < BK; kk += 32) {
            int h   = kk >> 5;
            int ckb = (kk >> 3) + quad;      // 16B-chunk column wanted
            short8 a[4], b[4], bd[4];
#pragma unroll
            for (int i = 0; i < 4; i++)
                a[i] = *(const short8*)(Ab + (wm + i * 16 + l16) * BK + (ckb ^ xa) * 8);
#pragma unroll
            for (int jj = 0; jj < 4; jj++)
                b[jj] = *(const short8*)(Bb + (wn + jj * 16 + l16) * BK + (ckb ^ xa) * 8);
#pragma unroll
            for (int jj = 0; jj < 4; jj++)
                bd[jj] = unpack_nib(q_cur[jj * 2 + h]);
#pragma unroll
            for (int i = 0; i < 4; i++)
#pragma unroll
                for (int jj = 0; jj < 4; jj++) {
                    acc_b[i][jj] = __builtin_amdgcn_mfma_f32_16x16x32_bf16(a[i], b[jj],  acc_b[i][jj], 0, 0, 0);
                    acc_d[i][jj] = __builtin_amdgcn_mfma_f32_16x16x32_bf16(a[i], bd[jj], acc_d[i][jj], 0, 0, 0);
                }
        }
        __syncthreads();   // drains next tile's loads + protects buf for re-stage
#pragma unroll
        for (int e = 0; e < 8; e++) q_cur[e] = q_nxt[e];
        buf ^= 1;
    }

    // section select for epilogue scales/zeros
    const int* qz; const float* sc; int r0, Osec;
    if (n0 < N_Q)            { qz = qz_q; sc = sc_q; r0 = n0;                Osec = N_Q;  }
    else if (n0 < N_Q + N_KV){ qz = qz_k; sc = sc_k; r0 = n0 - N_Q;          Osec = N_KV; }
    else                     { qz = qz_v; sc = sc_v; r0 = n0 - (N_Q + N_KV); Osec = N_KV; }

    // epilogue: C/D layout col = lane&15, row = quad*4 + reg  [m89/m91 verified]
    // out = bias + acc_b + s*acc_d - s*(129+z)*rowsumA
    float s4[4], cc4[4], bv4[4];
#pragma unroll
    for (int jj = 0; jj < 4; jj++) {
        int rsec = r0 + wn + jj * 16 + l16;
        float sv = sc[(size_t)d * Osec + rsec];
        int   zq = qz[(size_t)d * (Osec >> 3) + (rsec >> 3)];
        int   z  = (zq >> ((rsec & 7) * 4)) & 0xF;
        s4[jj]  = sv;
        cc4[jj] = sv * (float)(129 + z);
        bv4[jj] = bias[n0 + wn + jj * 16 + l16];
    }
#pragma unroll
    for (int i = 0; i < 4; i++) {
        int toks[4]; float rsv[4];
#pragma unroll
        for (int r = 0; r < 4; r++) {
            int row = m0 + wm + i * 16 + quad * 4 + r;
            toks[r] = perm[row];
            rsv[r]  = rs[row * 2] + rs[row * 2 + 1];
        }
#pragma unroll
        for (int jj = 0; jj < 4; jj++) {
            int col = n0 + wn + jj * 16 + l16;
#pragma unroll
            for (int r = 0; r < 4; r++) {
                int tok = toks[r];
                if (tok >= 0) {
                    float v = bv4[jj] + acc_b[i][jj][r] + s4[jj] * acc_d[i][jj][r] - cc4[jj] * rsv[r];
                    out[(size_t)tok * N_OUT + col] = v;
                }
            }
        }
    }
}

// ---------------------------------------------------------------------------
extern "C" void kernel_launch(void* const* d_in, const int* in_sizes, int n_in,
                              void* d_out, int out_size, void* d_ws, size_t ws_size,
                              hipStream_t stream) {
    const float* x      = (const float*)d_in[0];
    const float* w_base = (const float*)d_in[1];
    const float* bias   = (const float*)d_in[2];
    const int*   qw_q   = (const int*)d_in[3];
    const int*   qw_k   = (const int*)d_in[4];
    const int*   qw_v   = (const int*)d_in[5];
    const int*   qz_q   = (const int*)d_in[6];
    const int*   qz_k   = (const int*)d_in[7];
    const int*   qz_v   = (const int*)d_in[8];
    const float* sc_q   = (const float*)d_in[9];
    const float* sc_k   = (const float*)d_in[10];
    const float* sc_v   = (const float*)d_in[11];
    const int*   indices= (const int*)d_in[12];
    float* out = (float*)d_out;

    // workspace: wb16 [6144][4096] bf16 | Xp [1536][4096] bf16 | rs [1536][2] f32
    //          | perm [1536] | pofs [8] | qp [48][4][2][64][64][8] u32
    char* ws = (char*)d_ws;
    ushort* wb16 = (ushort*)ws;
    size_t wb_bytes = (size_t)N_OUT * K_IN * 2;                   // 50331648
    ushort* xp = (ushort*)(ws + wb_bytes);
    size_t xp_bytes = (size_t)PM_MAX * K_IN * 2;                  // 12582912
    float* rsum = (float*)(ws + wb_bytes + xp_bytes);
    size_t rs_bytes = (size_t)PM_MAX * 2 * sizeof(float);         // 12288
    int* perm = (int*)(ws + wb_bytes + xp_bytes + rs_bytes);
    int* pofs = perm + PM_MAX;
    uint* qp  = (uint*)(ws + wb_bytes + xp_bytes + rs_bytes + PM_MAX * 4 + 64);

    build_perm_kernel<<<1, 256, 0, stream>>>(indices, perm, pofs);
    wbconv_kernel<<<(N_OUT * K_IN / 8) / 256, 256, 0, stream>>>(w_base, wb16);
    repack_qw_kernel<<<48 * 4 * 2 * 8, 256, 0, stream>>>(qw_q, qw_k, qw_v, qp);
    build_xp_kernel<<<dim3(PM_MAX, 2), 256, 0, stream>>>(x, perm, xp, rsum);
    gemm_kernel<<<NBLK, 256, 0, stream>>>(xp, wb16, qp,
        qz_q, qz_k, qz_v, sc_q, sc_k, sc_v, bias,
        perm, pofs, rsum, out);
}

// Round 4
// 413.355 us; speedup vs baseline: 1.2498x; 1.0718x over previous
//
#include <hip/hip_runtime.h>
#include <stdint.h>

// Problem constants (from reference setup_inputs)
#define T_TOK 1024
#define K_IN  4096
#define N_OUT 6144
#define N_Q   4096
#define N_KV  1024
#define N_D   4
#define KP    512          // K_IN/8 packed int32 per row

// GEMM tiling
#define TM 64
#define TN 128
#define BK 64
#define NSTEPS (K_IN / BK)      // 64
#define PM_MAX 1280        // >= 1024 + 4*63 (worst-case 64-padding)
#define MT (PM_MAX/TM)     // 20
#define NT (N_OUT/TN)      // 48
#define NBLK (NT * MT)     // 960

// fused prep kernel block ranges
#define NB_WB ((N_OUT * K_IN / 8) / 256)   // 12288
#define NB_RP (48 * 4 * 2 * 8)             // 3072
#define NB_XP (PM_MAX * 2)                 // 2560

typedef __attribute__((ext_vector_type(8)))  short  short8;   // 8 x bf16 (4 VGPR) MFMA A/B frag
typedef __attribute__((ext_vector_type(4)))  float  float4v;  // MFMA C/D frag
typedef __attribute__((ext_vector_type(4)))  float  f32x4;
typedef __attribute__((ext_vector_type(4)))  uint   u32x4;

__device__ __forceinline__ ushort f2bf(float f) {
    uint32_t u = __float_as_uint(f);
    u = (u + 0x7FFFu + ((u >> 16) & 1u)) >> 16;   // RNE
    return (ushort)u;
}
__device__ __forceinline__ uint pack2(ushort a, ushort b) {
    return (uint)a | ((uint)b << 16);
}

// 8 nibbles of q -> short8 of bf16 values (128 + nib), exact.
// bf16 0x4300 = 128.0; mantissa has 7 bits so 128+n (n<=15) is exact.
// The +128 offset and the GPTQ zero-point are corrected in the epilogue
// via the row-sum of A:  s*acc_nib - s*(129+z)*rowsum(A).
__device__ __forceinline__ short8 unpack_nib(uint q) {
    union { u32x4 u; short8 s; } r;
    uint t1 = q >> 8, t2 = q >> 16, t3 = q >> 24;
    r.u.x = ((q  & 0xFu) | ((q  & 0xF0u) << 12)) | 0x43004300u;
    r.u.y = ((t1 & 0xFu) | ((t1 & 0xF0u) << 12)) | 0x43004300u;
    r.u.z = ((t2 & 0xFu) | ((t2 & 0xF0u) << 12)) | 0x43004300u;
    r.u.w = ((t3 & 0xFu) | ((t3 & 0xF0u) << 12)) | 0x43004300u;
    return r.s;
}

// ---------------------------------------------------------------------------
// K1: group tokens by adapter, fully parallel (1024 threads, one per token).
// perm[PM_MAX] = token index or -1 (padding); pofs[d] = padded segment starts
// (multiples of TM), pofs[N_D] = padded total.  Ballot-rank scatter: zero
// atomics, zero serial loops over tokens.
// ---------------------------------------------------------------------------
__global__ void build_perm_kernel(const int* __restrict__ indices,
                                  int* __restrict__ perm,
                                  int* __restrict__ pofs) {
    __shared__ int cw[16][4];   // per-wave counts
    __shared__ int pw[16][4];   // exclusive wave prefixes
    __shared__ int ps[N_D + 1];
    int tid = threadIdx.x;      // 1024 threads
    for (int p = tid; p < PM_MAX; p += 1024) perm[p] = -1;

    int d = indices[tid];
    unsigned long long m[4];
    m[0] = __ballot(d == 0); m[1] = __ballot(d == 1);
    m[2] = __ballot(d == 2); m[3] = __ballot(d == 3);
    int lane = tid & 63, wv = tid >> 6;
    if (lane < 4) cw[wv][lane] = (int)__popcll(m[lane]);
    __syncthreads();
    if (tid == 0) {
        int tot[4] = {0, 0, 0, 0};
        for (int w = 0; w < 16; w++)
            for (int dd = 0; dd < 4; dd++) { pw[w][dd] = tot[dd]; tot[dd] += cw[w][dd]; }
        int run = 0;
        for (int dd = 0; dd < N_D; dd++) { ps[dd] = run; run += ((tot[dd] + TM - 1) / TM) * TM; }
        ps[N_D] = run;
        for (int dd = 0; dd <= N_D; dd++) pofs[dd] = ps[dd];
    }
    __syncthreads();
    unsigned long long lt = (1ull << lane) - 1ull;
    int rank = pw[wv][d] + (int)__popcll(m[d] & lt);
    perm[ps[d] + rank] = tid;
}

// ---------------------------------------------------------------------------
// K2 (fused prep): three independent jobs partitioned by blockIdx range.
//  [0, NB_WB):          wb16[o][k] = bf16(w_base[o][k])        (150 MB traffic)
//  [NB_WB, +NB_RP):     repack qw -> qp in GEMM-lane order     (100 MB)
//  [.., +NB_XP):        Xp[pm][k] = bf16(x[perm[pm]][k]) + row-sums rs
// ---------------------------------------------------------------------------
__global__ void prep_kernel(const float* __restrict__ w_base, ushort* __restrict__ wb16,
                            const int* __restrict__ qw_q, const int* __restrict__ qw_k,
                            const int* __restrict__ qw_v, uint* __restrict__ qp,
                            const float* __restrict__ x, const int* __restrict__ perm,
                            ushort* __restrict__ xp, float* __restrict__ rs) {
    __shared__ int slds[64 * 64];
    int tid = threadIdx.x;
    int b = blockIdx.x;

    if (b < NB_WB) {
        // ---- wbconv ----
        int id = b * 256 + tid;                 // [0, N_OUT*K_IN/8)
        const f32x4* src = (const f32x4*)(w_base + (size_t)id * 8);
        f32x4 a = __builtin_nontemporal_load(src);
        f32x4 c = __builtin_nontemporal_load(src + 1);
        u32x4 packv;
        packv.x = pack2(f2bf(a.x), f2bf(a.y));
        packv.y = pack2(f2bf(a.z), f2bf(a.w));
        packv.z = pack2(f2bf(c.x), f2bf(c.y));
        packv.w = pack2(f2bf(c.z), f2bf(c.w));
        *(u32x4*)(wb16 + (size_t)id * 8) = packv;
        return;
    }
    b -= NB_WB;
    if (b < NB_RP) {
        // ---- repack qw: qp[bn][d][w2][s][lane][8], block = (bn,d,w2,s8) ----
        int s8 = b & 7;
        int r  = b >> 3;
        int w2 = r & 1; r >>= 1;
        int d  = r & 3;
        int bn = r >> 2;
        const int* qw; int r0, Osec;
        if (bn < 32)      { qw = qw_q; r0 = bn * 128;        Osec = N_Q;  }
        else if (bn < 40) { qw = qw_k; r0 = (bn - 32) * 128; Osec = N_KV; }
        else              { qw = qw_v; r0 = (bn - 40) * 128; Osec = N_KV; }
#pragma unroll
        for (int k = 0; k < 4; k++) {
            int p   = k * 256 + tid;       // dwordx4 index [0,1024)
            int row = p >> 4, c4 = p & 15;
            const int* src = qw + ((size_t)d * Osec + r0 + w2 * 64 + row) * KP + s8 * 64 + c4 * 4;
            *(u32x4*)&slds[row * 64 + c4 * 4] = *(const u32x4*)src;
        }
        __syncthreads();
        size_t obase = (size_t)b * 4096;   // 4096 uints per block slab
#pragma unroll
        for (int k = 0; k < 2; k++) {
            int p    = k * 256 + tid;      // packet index [0,512)
            int sl   = p >> 6, lane = p & 63;
            int quad = lane >> 4, l16 = lane & 15;
            uint pk[8];
#pragma unroll
            for (int e = 0; e < 8; e++) {
                int jj = e >> 1, h = e & 1;
                pk[e] = (uint)slds[(jj * 16 + l16) * 64 + sl * 8 + h * 4 + quad];
            }
            *(u32x4*)(qp + obase + (size_t)p * 8)     = *(u32x4*)&pk[0];
            *(u32x4*)(qp + obase + (size_t)p * 8 + 4) = *(u32x4*)&pk[4];
        }
        return;
    }
    b -= NB_RP;
    {
        // ---- build_xp ----
        int pm = b >> 1;
        int half = b & 1;
        int c0 = half * (K_IN / 2) + tid * 8;
        int tok = perm[pm];
        ushort res[8];
        if (tok < 0) {
#pragma unroll
            for (int j = 0; j < 8; j++) res[j] = 0;
        } else {
            const f32x4* src = (const f32x4*)(x + (size_t)tok * K_IN + c0);
            f32x4 a = __builtin_nontemporal_load(src);
            f32x4 c = __builtin_nontemporal_load(src + 1);
            float v[8] = {a.x, a.y, a.z, a.w, c.x, c.y, c.z, c.w};
#pragma unroll
            for (int j = 0; j < 8; j++) res[j] = f2bf(v[j]);
        }
        u32x4 packv;
        packv.x = pack2(res[0], res[1]); packv.y = pack2(res[2], res[3]);
        packv.z = pack2(res[4], res[5]); packv.w = pack2(res[6], res[7]);
        *(u32x4*)(xp + (size_t)pm * K_IN + c0) = packv;

        // row-sum of the EXACT bf16 values the MFMA will consume
        float ssum = 0.f;
#pragma unroll
        for (int j = 0; j < 8; j++) ssum += __uint_as_float((uint)res[j] << 16);
#pragma unroll
        for (int off = 32; off > 0; off >>= 1) ssum += __shfl_xor(ssum, off);
        float* wsum = (float*)slds;
        if ((tid & 63) == 0) wsum[tid >> 6] = ssum;
        __syncthreads();
        if (tid == 0) rs[pm * 2 + half] = wsum[0] + wsum[1] + wsum[2] + wsum[3];
    }
}

// ---------------------------------------------------------------------------
// K3: full-K GEMM with fused GPTQ delta (no split-K, direct store).
// TM=64 tile: LDS 48 KB -> 3 blocks/CU (latency hiding for the per-step
// barrier drain), halved acc registers, <=63 padding rows per segment.
// Base path: LDS-staged shared wb16 B-tile (global_load_lds, XOR swizzle).
// Delta path: repacked qp packets, 2 coalesced dwordx4 per lane per step,
// prefetched one step ahead; unpacked to bf16 (128+nib) frags with bit-ops,
// fed to a second MFMA chain.
// Epilogue: out = bias + acc_base + s*acc_nib - s*(129+z)*rowsumA.
// (Resubmit of round-3 source: bench infra failed before any dispatch ran.)
// ---------------------------------------------------------------------------
__global__ __launch_bounds__(256, 3) void gemm_kernel(
    const ushort* __restrict__ xp, const ushort* __restrict__ wb16,
    const uint* __restrict__ qp,
    const int* __restrict__ qz_q, const int* __restrict__ qz_k, const int* __restrict__ qz_v,
    const float* __restrict__ sc_q, const float* __restrict__ sc_k, const float* __restrict__ sc_v,
    const float* __restrict__ bias,
    const int* __restrict__ perm, const int* __restrict__ pofs,
    const float* __restrict__ rs,
    float* __restrict__ out) {

    __shared__ ushort As[2][TM * BK];   // 2 x 8 KB
    __shared__ ushort Bs[2][TN * BK];   // 2 x 16 KB

    // XCD-pinned decode: all blocks of one bn share lin%8 -> same XCD L2.
    int lin  = blockIdx.x;              // [0, 960)
    int low3 = lin & 7, rest = lin >> 3;
    int bm   = rest % MT, bq = rest / MT;
    int bn   = bq * 8 + low3;

    int m0 = bm * TM, n0 = bn * TN;
    int ptot = pofs[N_D];
    if (m0 >= ptot) return;                       // uniform per block
    int d = 0;
    while (d < N_D - 1 && m0 >= pofs[d + 1]) d++; // tile fully inside segment d

    int tid  = threadIdx.x;
    int lane = tid & 63;
    int wv   = tid >> 6;
    int wm   = (wv & 1) * 32;
    int wn   = (wv >> 1) * 64;
    int quad = lane >> 4;
    int l16  = lane & 15;
    int xa   = l16 & 7;          // read-side swizzle term

    // delta packet base for this wave: qp[bn][d][w2][s][lane][8]
    const uint* qpw = qp + (((size_t)(bn * 4 + d) * 2 + (wv >> 1)) * 64 * 64 * 8)
                         + (size_t)lane * 8;

    const float4v zero4 = {0.f, 0.f, 0.f, 0.f};
    float4v acc_b[2][4], acc_d[2][4];
#pragma unroll
    for (int i = 0; i < 2; i++)
#pragma unroll
        for (int jj = 0; jj < 4; jj++) { acc_b[i][jj] = zero4; acc_d[i][jj] = zero4; }

    // stage one BK-tile (A+B) into the given LDS buffers; 16B/lane, XOR swizzle
    auto stage = [&](ushort* dstA, ushort* dstB, int k0) {
#pragma unroll
        for (int w = 0; w < 2; w++) {
            int p   = w * 256 + tid;
            int row = p >> 3;
            int ckl = (p & 7) ^ (row & 7);
            const ushort* ga = xp + (size_t)(m0 + row) * K_IN + k0 + ckl * 8;
            int base = (w * 256 + (tid & ~63)) * 8;   // wave-uniform ushort offset
            __builtin_amdgcn_global_load_lds((const __attribute__((address_space(1))) void*)ga,
                                             (__attribute__((address_space(3))) void*)(dstA + base), 16, 0, 0);
        }
#pragma unroll
        for (int w = 0; w < 4; w++) {
            int p   = w * 256 + tid;
            int row = p >> 3;
            int ckl = (p & 7) ^ (row & 7);
            const ushort* gb = wb16 + (size_t)(n0 + row) * K_IN + k0 + ckl * 8;
            int base = (w * 256 + (tid & ~63)) * 8;
            __builtin_amdgcn_global_load_lds((const __attribute__((address_space(1))) void*)gb,
                                             (__attribute__((address_space(3))) void*)(dstB + base), 16, 0, 0);
        }
    };

    int buf = 0;
    stage(As[0], Bs[0], 0);
    uint q_cur[8];
    *(u32x4*)&q_cur[0] = *(const u32x4*)(qpw);
    *(u32x4*)&q_cur[4] = *(const u32x4*)(qpw + 4);
    __syncthreads();

    for (int s = 0; s < NSTEPS; s++) {
        uint q_nxt[8];
        if (s + 1 < NSTEPS) {
            stage(As[1 - buf], Bs[1 - buf], (s + 1) * BK);
            const uint* qn = qpw + (size_t)(s + 1) * 512;
            *(u32x4*)&q_nxt[0] = *(const u32x4*)(qn);
            *(u32x4*)&q_nxt[4] = *(const u32x4*)(qn + 4);
        }

        const ushort* Ab = As[buf];
        const ushort* Bb = Bs[buf];
#pragma unroll
        for (int kk = 0; kk < BK; kk += 32) {
            int h   = kk >> 5;
            int ckb = (kk >> 3) + quad;      // 16B-chunk column wanted
            short8 a[2], b[4], bd[4];
#pragma unroll
            for (int i = 0; i < 2; i++)
                a[i] = *(const short8*)(Ab + (wm + i * 16 + l16) * BK + (ckb ^ xa) * 8);
#pragma unroll
            for (int jj = 0; jj < 4; jj++)
                b[jj] = *(const short8*)(Bb + (wn + jj * 16 + l16) * BK + (ckb ^ xa) * 8);
#pragma unroll
            for (int jj = 0; jj < 4; jj++)
                bd[jj] = unpack_nib(q_cur[jj * 2 + h]);
#pragma unroll
            for (int i = 0; i < 2; i++)
#pragma unroll
                for (int jj = 0; jj < 4; jj++) {
                    acc_b[i][jj] = __builtin_amdgcn_mfma_f32_16x16x32_bf16(a[i], b[jj],  acc_b[i][jj], 0, 0, 0);
                    acc_d[i][jj] = __builtin_amdgcn_mfma_f32_16x16x32_bf16(a[i], bd[jj], acc_d[i][jj], 0, 0, 0);
                }
        }
        __syncthreads();   // drains next tile's loads + protects buf for re-stage
#pragma unroll
        for (int e = 0; e < 8; e++) q_cur[e] = q_nxt[e];
        buf ^= 1;
    }

    // section select for epilogue scales/zeros
    const int* qz; const float* sc; int r0, Osec;
    if (n0 < N_Q)            { qz = qz_q; sc = sc_q; r0 = n0;                Osec = N_Q;  }
    else if (n0 < N_Q + N_KV){ qz = qz_k; sc = sc_k; r0 = n0 - N_Q;          Osec = N_KV; }
    else                     { qz = qz_v; sc = sc_v; r0 = n0 - (N_Q + N_KV); Osec = N_KV; }

    // epilogue: C/D layout col = lane&15, row = quad*4 + reg  [m89/m91 verified]
    // out = bias + acc_b + s*acc_d - s*(129+z)*rowsumA
    float s4[4], cc4[4], bv4[4];
#pragma unroll
    for (int jj = 0; jj < 4; jj++) {
        int rsec = r0 + wn + jj * 16 + l16;
        float sv = sc[(size_t)d * Osec + rsec];
        int   zq = qz[(size_t)d * (Osec >> 3) + (rsec >> 3)];
        int   z  = (zq >> ((rsec & 7) * 4)) & 0xF;
        s4[jj]  = sv;
        cc4[jj] = sv * (float)(129 + z);
        bv4[jj] = bias[n0 + wn + jj * 16 + l16];
    }
#pragma unroll
    for (int i = 0; i < 2; i++) {
        int toks[4]; float rsv[4];
#pragma unroll
        for (int r = 0; r < 4; r++) {
            int row = m0 + wm + i * 16 + quad * 4 + r;
            toks[r] = perm[row];
            rsv[r]  = rs[row * 2] + rs[row * 2 + 1];
        }
#pragma unroll
        for (int jj = 0; jj < 4; jj++) {
            int col = n0 + wn + jj * 16 + l16;
#pragma unroll
            for (int r = 0; r < 4; r++) {
                int tok = toks[r];
                if (tok >= 0) {
                    float v = bv4[jj] + acc_b[i][jj][r] + s4[jj] * acc_d[i][jj][r] - cc4[jj] * rsv[r];
                    out[(size_t)tok * N_OUT + col] = v;
                }
            }
        }
    }
}

// ---------------------------------------------------------------------------
extern "C" void kernel_launch(void* const* d_in, const int* in_sizes, int n_in,
                              void* d_out, int out_size, void* d_ws, size_t ws_size,
                              hipStream_t stream) {
    const float* x      = (const float*)d_in[0];
    const float* w_base = (const float*)d_in[1];
    const float* bias   = (const float*)d_in[2];
    const int*   qw_q   = (const int*)d_in[3];
    const int*   qw_k   = (const int*)d_in[4];
    const int*   qw_v   = (const int*)d_in[5];
    const int*   qz_q   = (const int*)d_in[6];
    const int*   qz_k   = (const int*)d_in[7];
    const int*   qz_v   = (const int*)d_in[8];
    const float* sc_q   = (const float*)d_in[9];
    const float* sc_k   = (const float*)d_in[10];
    const float* sc_v   = (const float*)d_in[11];
    const int*   indices= (const int*)d_in[12];
    float* out = (float*)d_out;

    // workspace: wb16 [6144][4096] bf16 | Xp [1280][4096] bf16 | rs [1280][2] f32
    //          | perm [1280] | pofs | qp [48][4][2][64][64][8] u32
    char* ws = (char*)d_ws;
    ushort* wb16 = (ushort*)ws;
    size_t wb_bytes = (size_t)N_OUT * K_IN * 2;                   // 50331648
    ushort* xp = (ushort*)(ws + wb_bytes);
    size_t xp_bytes = (size_t)PM_MAX * K_IN * 2;                  // 10485760
    float* rsum = (float*)(ws + wb_bytes + xp_bytes);
    size_t rs_bytes = (size_t)PM_MAX * 2 * sizeof(float);         // 10240
    int* perm = (int*)(ws + wb_bytes + xp_bytes + rs_bytes);
    int* pofs = perm + PM_MAX;
    uint* qp  = (uint*)(ws + wb_bytes + xp_bytes + rs_bytes + PM_MAX * 4 + 64);

    build_perm_kernel<<<1, 1024, 0, stream>>>(indices, perm, pofs);
    prep_kernel<<<NB_WB + NB_RP + NB_XP, 256, 0, stream>>>(
        w_base, wb16, qw_q, qw_k, qw_v, qp, x, perm, xp, rsum);
    gemm_kernel<<<NBLK, 256, 0, stream>>>(xp, wb16, qp,
        qz_q, qz_k, qz_v, sc_q, sc_k, sc_v, bias,
        perm, pofs, rsum, out);
}